// Round 3
// baseline (588.053 us; speedup 1.0000x reference)
//
#include <hip/hip_runtime.h>
#include <cstdint>

typedef unsigned short u16;
typedef u16 u16x8 __attribute__((ext_vector_type(8)));
typedef __bf16 bf16x8 __attribute__((ext_vector_type(8)));
typedef float f32x4 __attribute__((ext_vector_type(4)));

#define DEV static __device__ __forceinline__

// problem constants
constexpr int NT = 8192;         // tokens
constexpr int NP = NT * 2;       // 16384 (token, k) pairs
constexpr int NE = 8;
constexpr int DM = 1024;
constexpr int DF = 2048;
constexpr int MAXS = 17408;      // >= 16384 + 8*127 alignment slack
constexpr int MAXTILES = 136;    // >= 128 + 7

DEV u16 f2bf(float f) {          // RTNE float -> bf16 bits
  uint32_t u = __builtin_bit_cast(uint32_t, f);
  u += 0x7fffu + ((u >> 16) & 1u);
  return (u16)(u >> 16);
}

DEV void gload16(const void* g, void* l) {
  __builtin_amdgcn_global_load_lds((const __attribute__((address_space(1))) void*)g,
                                   (__attribute__((address_space(3))) void*)l, 16, 0, 0);
}

DEV bf16x8 ldfrag(const char* p) { return __builtin_bit_cast(bf16x8, *(const u16x8*)p); }

// ---- routing ----
__global__ void k_init(int* meta, int* slot_token) {
  const int i = blockIdx.x * 256 + threadIdx.x;
  if (i < 32) meta[i] = 0;
  if (i < MAXS) slot_token[i] = -1;
}

__global__ void k_count(const int* __restrict__ eidx, int* meta) {
  const int p = blockIdx.x * 256 + threadIdx.x;
  if (p < NP) atomicAdd(&meta[eidx[p] & 7], 1);
}

__global__ void k_scan(int* meta) {
  if (threadIdx.x == 0 && blockIdx.x == 0) {
    int off = 0, ti = 0;
    for (int e = 0; e < NE; ++e) {
      meta[16 + e] = off;
      const int c = meta[e];
      off += ((c + 127) >> 7) << 7;
      for (int mt = 0; mt * 128 < c; ++mt) meta[32 + ti++] = e | (mt << 8);
    }
    meta[24] = off;
    meta[25] = ti;
  }
}

__global__ void k_fill(const int* __restrict__ eidx, const float* __restrict__ ew,
                       int* meta, int* slot_token, float* slot_weight) {
  const int p = blockIdx.x * 256 + threadIdx.x;
  if (p < NP) {
    const int e = eidx[p] & 7;
    const int pos = meta[16 + e] + atomicAdd(&meta[8 + e], 1);
    slot_token[pos]  = p >> 1;
    slot_weight[pos] = ew[p];
  }
}

__global__ void k_gather(const float* __restrict__ x, const int* __restrict__ slot_token,
                         u16* __restrict__ Xg) {
  const int s = blockIdx.x;
  const int tok = slot_token[s];
  const int c = threadIdx.x * 4;
  alignas(8) u16 b[4] = {0, 0, 0, 0};
  if (tok >= 0) {
    const float4 v = *reinterpret_cast<const float4*>(x + (size_t)tok * DM + c);
    b[0] = f2bf(v.x); b[1] = f2bf(v.y); b[2] = f2bf(v.z); b[3] = f2bf(v.w);
  }
  *reinterpret_cast<uint2*>(Xg + (size_t)s * DM + c) = *reinterpret_cast<const uint2*>(b);
}

// src [K][N] fp32 -> dst [N][K] bf16
__global__ void k_transpose(const float* __restrict__ src, u16* __restrict__ dst, int K, int N) {
  const size_t mo = (size_t)blockIdx.z * K * N;
  const float* s = src + mo;
  u16* d = dst + mo;
  const int n0 = blockIdx.x * 64, k0 = blockIdx.y * 64;
  __shared__ u16 tile[64][72];
  const int t = threadIdx.x;
  const int r = t >> 4, cb = (t & 15) * 4;
#pragma unroll
  for (int it = 0; it < 4; ++it) {
    const float4 v = *reinterpret_cast<const float4*>(s + (size_t)(k0 + r + it * 16) * N + n0 + cb);
    tile[r + it * 16][cb + 0] = f2bf(v.x);
    tile[r + it * 16][cb + 1] = f2bf(v.y);
    tile[r + it * 16][cb + 2] = f2bf(v.z);
    tile[r + it * 16][cb + 3] = f2bf(v.w);
  }
  __syncthreads();
  const int nl = t >> 2, ks = (t & 3) * 16;
  alignas(16) u16 vals[16];
#pragma unroll
  for (int j = 0; j < 16; ++j) vals[j] = tile[ks + j][nl];
  u16* dp = d + (size_t)(n0 + nl) * K + k0 + ks;
  *reinterpret_cast<uint4*>(dp)     = *reinterpret_cast<const uint4*>(vals);
  *reinterpret_cast<uint4*>(dp + 8) = *reinterpret_cast<const uint4*>(vals + 8);
}

// GEMM1: H = silu(Xg @ w1^T') * (Xg @ w2^T')
// tile 128x128, 4 waves (2x2), per-wave 64x64 dual; BK=32; v-swizzled LDS (conflict-free)
__global__ __launch_bounds__(256, 2)
void k_gemm1(const u16* __restrict__ Xg, const u16* __restrict__ w1T, const u16* __restrict__ w2T,
             u16* __restrict__ H, const int* __restrict__ meta) {
  const int ti = blockIdx.y;
  if (ti >= meta[25]) return;
  const int ent = meta[32 + ti];
  const int e = ent & 255, mt = ent >> 8;
  const int base = meta[16 + e];
  const int n0 = blockIdx.x * 128;

  // buffer: A[128][64B] @0 | B1 @8192 | B2 @16384  (24KB, x2 dbuf = 48KB)
  __shared__ __align__(16) char sm[2][24576];

  const int tid = threadIdx.x;
  const int lane = tid & 63;
  const int w = tid >> 6;
  const int wr = w >> 1, wc = w & 1;
  const int lrow = lane & 15, lk = lane >> 4;
  const int rw = lane >> 2;                                    // staging row-in-chunk
  const int SC = (((lane) ^ (lane >> 2) ^ (lane >> 4)) & 3) << 4; // swizzle col (read & write)

  const char* Ag  = (const char*)(Xg + (size_t)(base + mt * 128) * DM);
  const char* B1g = (const char*)(w1T + ((size_t)e * DF + n0) * DM);
  const char* B2g = (const char*)(w2T + ((size_t)e * DF + n0) * DM);

  f32x4 acc1[4][4] = {};
  f32x4 acc2[4][4] = {};

  auto STAGE = [&](int buf, int k0) {
    const int kb = k0 * 2;
    char* s = sm[buf];
    gload16(Ag  + (size_t)((w * 16) + rw) * 2048 + kb + SC,       s + w * 1024);
    gload16(Ag  + (size_t)((64 + w * 16) + rw) * 2048 + kb + SC,  s + 4096 + w * 1024);
    gload16(B1g + (size_t)((w * 16) + rw) * 2048 + kb + SC,       s + 8192 + w * 1024);
    gload16(B1g + (size_t)((64 + w * 16) + rw) * 2048 + kb + SC,  s + 8192 + 4096 + w * 1024);
    gload16(B2g + (size_t)((w * 16) + rw) * 2048 + kb + SC,       s + 16384 + w * 1024);
    gload16(B2g + (size_t)((64 + w * 16) + rw) * 2048 + kb + SC,  s + 16384 + 4096 + w * 1024);
  };

  STAGE(0, 0);
  asm volatile("s_waitcnt vmcnt(0)" ::: "memory");
  __syncthreads();

  int cur = 0;
  for (int k0 = 0; k0 < DM; k0 += 32) {
    if (k0 + 32 < DM) STAGE(cur ^ 1, k0 + 32);
    const char* s = sm[cur];
    bf16x8 a[4], b1[4], b2[4];
#pragma unroll
    for (int m = 0; m < 4; ++m)
      a[m] = ldfrag(s + (wr * 64 + m * 16 + lrow) * 64 + SC);
#pragma unroll
    for (int n = 0; n < 4; ++n) {
      b1[n] = ldfrag(s + 8192  + (wc * 64 + n * 16 + lrow) * 64 + SC);
      b2[n] = ldfrag(s + 16384 + (wc * 64 + n * 16 + lrow) * 64 + SC);
    }
#pragma unroll
    for (int m = 0; m < 4; ++m)
#pragma unroll
      for (int n = 0; n < 4; ++n) {
        acc1[m][n] = __builtin_amdgcn_mfma_f32_16x16x32_bf16(a[m], b1[n], acc1[m][n], 0, 0, 0);
        acc2[m][n] = __builtin_amdgcn_mfma_f32_16x16x32_bf16(a[m], b2[n], acc2[m][n], 0, 0, 0);
      }
    asm volatile("s_waitcnt vmcnt(0)" ::: "memory");
    __syncthreads();
    cur ^= 1;
  }

  u16* Hrow = H + (size_t)(base + mt * 128) * DF + n0;
#pragma unroll
  for (int m = 0; m < 4; ++m)
#pragma unroll
    for (int r = 0; r < 4; ++r) {
      const int rl = wr * 64 + m * 16 + lk * 4 + r;
      u16* hp = Hrow + (size_t)rl * DF + wc * 64 + lrow;
#pragma unroll
      for (int n = 0; n < 4; ++n) {
        const float h1 = acc1[m][n][r], h2 = acc2[m][n][r];
        const float sv = h1 / (1.f + __expf(-h1)) * h2;   // silu(h1)*h2
        hp[n * 16] = f2bf(sv);
      }
    }
}

// GEMM2: out[token] += wgt * (H @ w3^T')
// tile 128x128, 2 waves, per-wave 64x128; BK=32; swizzled LDS; 4 blocks/CU
__global__ __launch_bounds__(128, 2)
void k_gemm2(const u16* __restrict__ H, const u16* __restrict__ w3T, const int* __restrict__ meta,
             const int* __restrict__ slot_token, const float* __restrict__ slot_weight,
             float* __restrict__ out) {
  const int ti = blockIdx.y;
  if (ti >= meta[25]) return;
  const int ent = meta[32 + ti];
  const int e = ent & 255, mt = ent >> 8;
  const int base = meta[16 + e];
  const int n0 = blockIdx.x * 128;

  // buffer: A[128][64B] @0 | B[128][64B] @8192  (16KB, x2 dbuf = 32KB)
  __shared__ __align__(16) char sm[2][16384];

  const int tid = threadIdx.x;
  const int lane = tid & 63;
  const int w = tid >> 6;                                      // 0..1
  const int lrow = lane & 15, lk = lane >> 4;
  const int rw = lane >> 2;
  const int SC = (((lane) ^ (lane >> 2) ^ (lane >> 4)) & 3) << 4;

  const char* Ag = (const char*)(H + (size_t)(base + mt * 128) * DF);
  const char* Bg = (const char*)(w3T + ((size_t)e * DM + n0) * DF);

  f32x4 acc[4][8] = {};

  auto STAGE = [&](int buf, int k0) {
    const int kb = k0 * 2;
    char* s = sm[buf];
#pragma unroll
    for (int j = 0; j < 4; ++j) {
      const int rb = (j * 2 + w) * 16;
      gload16(Ag + (size_t)(rb + rw) * 4096 + kb + SC, s + rb * 64);
      gload16(Bg + (size_t)(rb + rw) * 4096 + kb + SC, s + 8192 + rb * 64);
    }
  };

  STAGE(0, 0);
  asm volatile("s_waitcnt vmcnt(0)" ::: "memory");
  __syncthreads();

  int cur = 0;
  for (int k0 = 0; k0 < DF; k0 += 32) {
    if (k0 + 32 < DF) STAGE(cur ^ 1, k0 + 32);
    const char* s = sm[cur];
    bf16x8 a[4], b[8];
#pragma unroll
    for (int m = 0; m < 4; ++m)
      a[m] = ldfrag(s + (w * 64 + m * 16 + lrow) * 64 + SC);
#pragma unroll
    for (int n = 0; n < 8; ++n)
      b[n] = ldfrag(s + 8192 + (n * 16 + lrow) * 64 + SC);
#pragma unroll
    for (int m = 0; m < 4; ++m)
#pragma unroll
      for (int n = 0; n < 8; ++n)
        acc[m][n] = __builtin_amdgcn_mfma_f32_16x16x32_bf16(a[m], b[n], acc[m][n], 0, 0, 0);
    asm volatile("s_waitcnt vmcnt(0)" ::: "memory");
    __syncthreads();
    cur ^= 1;
  }

  const int sb = base + mt * 128;
#pragma unroll
  for (int m = 0; m < 4; ++m)
#pragma unroll
    for (int r = 0; r < 4; ++r) {
      const int rl = w * 64 + m * 16 + lk * 4 + r;
      const int tok = slot_token[sb + rl];
      const float wgt = slot_weight[sb + rl];
      if (tok >= 0) {
        float* op = out + (size_t)tok * DM + n0 + lrow;
#pragma unroll
        for (int n = 0; n < 8; ++n)
          atomicAdd(op + n * 16, wgt * acc[m][n][r]);
      }
    }
}

extern "C" void kernel_launch(void* const* d_in, const int* in_sizes, int n_in,
                              void* d_out, int out_size, void* d_ws, size_t ws_size,
                              hipStream_t stream) {
  const float* x  = (const float*)d_in[0];
  const int* eidx = (const int*)d_in[1];
  const float* ew = (const float*)d_in[2];
  const float* w1 = (const float*)d_in[3];
  const float* w2 = (const float*)d_in[4];
  const float* w3 = (const float*)d_in[5];
  float* out = (float*)d_out;
  char* ws = (char*)d_ws;

  int* meta          = (int*)ws;
  int* slot_token    = (int*)(ws + 1024);
  float* slot_weight = (float*)(ws + 1024 + (size_t)MAXS * 4);
  size_t off = 1024 + (size_t)MAXS * 8;
  u16* Xg  = (u16*)(ws + off); off += (size_t)MAXS * DM * 2;
  u16* w1T = (u16*)(ws + off); off += (size_t)NE * DM * DF * 2;
  u16* w2T = (u16*)(ws + off); off += (size_t)NE * DM * DF * 2;
  u16* w3T = (u16*)(ws + off); off += (size_t)NE * DM * DF * 2;
  u16* H   = (u16*)(ws + off);  // MAXS * DF * 2 bytes

  hipMemsetAsync(d_out, 0, (size_t)NT * DM * 4, stream);
  k_init<<<(MAXS + 255) / 256, 256, 0, stream>>>(meta, slot_token);
  k_count<<<NP / 256, 256, 0, stream>>>(eidx, meta);
  k_scan<<<1, 64, 0, stream>>>(meta);
  k_fill<<<NP / 256, 256, 0, stream>>>(eidx, ew, meta, slot_token, slot_weight);
  k_gather<<<MAXS, 256, 0, stream>>>(x, slot_token, Xg);
  k_transpose<<<dim3(DF / 64, DM / 64, NE), 256, 0, stream>>>(w1, w1T, DM, DF);
  k_transpose<<<dim3(DF / 64, DM / 64, NE), 256, 0, stream>>>(w2, w2T, DM, DF);
  k_transpose<<<dim3(DM / 64, DF / 64, NE), 256, 0, stream>>>(w3, w3T, DF, DM);
  k_gemm1<<<dim3(DF / 128, MAXTILES, 1), 256, 0, stream>>>(Xg, w1T, w2T, H, meta);
  k_gemm2<<<dim3(DM / 128, MAXTILES, 1), 128, 0, stream>>>(H, w3T, meta, slot_token, slot_weight, out);
}

// Round 4
// 517.902 us; speedup vs baseline: 1.1355x; 1.1355x over previous
//
#include <hip/hip_runtime.h>
#include <cstdint>

typedef unsigned short u16;
typedef u16 u16x8 __attribute__((ext_vector_type(8)));
typedef __bf16 bf16x8 __attribute__((ext_vector_type(8)));
typedef float f32x4 __attribute__((ext_vector_type(4)));

#define DEV static __device__ __forceinline__

// problem constants
constexpr int NT = 8192;         // tokens
constexpr int NP = NT * 2;       // 16384 (token, k) pairs
constexpr int NE = 8;
constexpr int DM = 1024;
constexpr int DF = 2048;
constexpr int MAXS = 17408;      // >= 16384 + 8*127 alignment slack
constexpr int MAXTILES = 136;    // >= 128 + 7

DEV u16 f2bf(float f) {          // RTNE float -> bf16 bits
  uint32_t u = __builtin_bit_cast(uint32_t, f);
  u += 0x7fffu + ((u >> 16) & 1u);
  return (u16)(u >> 16);
}

DEV void gload16(const void* g, void* l) {
  __builtin_amdgcn_global_load_lds((const __attribute__((address_space(1))) void*)g,
                                   (__attribute__((address_space(3))) void*)l, 16, 0, 0);
}

DEV bf16x8 ldfrag(const char* p) { return __builtin_bit_cast(bf16x8, *(const u16x8*)p); }

// ---- routing ----
// meta[0..7]=counts, [8..15]=cursor, [16..23]=padded offsets, [24]=total rows,
// [25]=num tiles, [32..32+MAXTILES)=tile table (expert | mtile<<8)
__global__ void k_init(int* meta, int* slot_token) {
  const int i = blockIdx.x * 256 + threadIdx.x;
  if (i < 32) meta[i] = 0;
  if (i < MAXS) slot_token[i] = -1;
}

__global__ void k_count(const int* __restrict__ eidx, int* meta) {
  const int p = blockIdx.x * 256 + threadIdx.x;
  if (p < NP) atomicAdd(&meta[eidx[p] & 7], 1);
}

__global__ void k_scan(int* meta) {
  if (threadIdx.x == 0 && blockIdx.x == 0) {
    int off = 0, ti = 0;
    for (int e = 0; e < NE; ++e) {
      meta[16 + e] = off;
      const int c = meta[e];
      off += ((c + 127) >> 7) << 7;
      for (int mt = 0; mt * 128 < c; ++mt) meta[32 + ti++] = e | (mt << 8);
    }
    meta[24] = off;
    meta[25] = ti;
  }
}

__global__ void k_fill(const int* __restrict__ eidx, const float* __restrict__ ew,
                       int* meta, int* slot_token, float* slot_weight, int* pair_slot) {
  const int p = blockIdx.x * 256 + threadIdx.x;
  if (p < NP) {
    const int e = eidx[p] & 7;
    const int pos = meta[16 + e] + atomicAdd(&meta[8 + e], 1);
    slot_token[pos]  = p >> 1;
    slot_weight[pos] = ew[p];
    pair_slot[p] = pos;
  }
}

// gather selected token rows -> bf16, zeros for padding slots
__global__ void k_gather(const float* __restrict__ x, const int* __restrict__ slot_token,
                         u16* __restrict__ Xg) {
  const int s = blockIdx.x;
  const int tok = slot_token[s];
  const int c = threadIdx.x * 4;
  alignas(8) u16 b[4] = {0, 0, 0, 0};
  if (tok >= 0) {
    const float4 v = *reinterpret_cast<const float4*>(x + (size_t)tok * DM + c);
    b[0] = f2bf(v.x); b[1] = f2bf(v.y); b[2] = f2bf(v.z); b[3] = f2bf(v.w);
  }
  *reinterpret_cast<uint2*>(Xg + (size_t)s * DM + c) = *reinterpret_cast<const uint2*>(b);
}

// src [K][N] fp32 -> dst [N][K] bf16
__global__ void k_transpose(const float* __restrict__ src, u16* __restrict__ dst, int K, int N) {
  const size_t mo = (size_t)blockIdx.z * K * N;
  const float* s = src + mo;
  u16* d = dst + mo;
  const int n0 = blockIdx.x * 64, k0 = blockIdx.y * 64;
  __shared__ u16 tile[64][72];
  const int t = threadIdx.x;
  const int r = t >> 4, cb = (t & 15) * 4;
#pragma unroll
  for (int it = 0; it < 4; ++it) {
    const float4 v = *reinterpret_cast<const float4*>(s + (size_t)(k0 + r + it * 16) * N + n0 + cb);
    tile[r + it * 16][cb + 0] = f2bf(v.x);
    tile[r + it * 16][cb + 1] = f2bf(v.y);
    tile[r + it * 16][cb + 2] = f2bf(v.z);
    tile[r + it * 16][cb + 3] = f2bf(v.w);
  }
  __syncthreads();
  const int nl = t >> 2, ks = (t & 3) * 16;
  alignas(16) u16 vals[16];
#pragma unroll
  for (int j = 0; j < 16; ++j) vals[j] = tile[ks + j][nl];
  u16* dp = d + (size_t)(n0 + nl) * K + k0 + ks;
  *reinterpret_cast<uint4*>(dp)     = *reinterpret_cast<const uint4*>(vals);
  *reinterpret_cast<uint4*>(dp + 8) = *reinterpret_cast<const uint4*>(vals + 8);
}

// GEMM1: H = silu(Xg @ w1^T') * (Xg @ w2^T')
// tile 128x64, BK=32, 2-phase prefetch, per-wave 64x32 dual (64 AGPR)  [R2-proven]
__global__ __launch_bounds__(256, 3)
void k_gemm1(const u16* __restrict__ Xg, const u16* __restrict__ w1T, const u16* __restrict__ w2T,
             u16* __restrict__ H, const int* __restrict__ meta) {
  const int ti = blockIdx.y;
  if (ti >= meta[25]) return;
  const int ent = meta[32 + ti];
  const int e = ent & 255, mt = ent >> 8;
  const int base = meta[16 + e];
  const int n0 = blockIdx.x * 64;

  // per buffer: A[128][32] @0 (8KB) | B1[64][32] @8192 (4KB) | B2[64][32] @12288 (4KB)
  __shared__ __align__(16) char sm[2][16384];

  const int tid = threadIdx.x;
  const int lane = tid & 63;
  const int w = tid >> 6;
  const int wr = w >> 1, wc = w & 1;
  const int lrow = lane & 15, lk = lane >> 4;
  const int srow = tid >> 2;
  const int scolb = (tid & 3) * 16;

  const char* Ag  = (const char*)(Xg + (size_t)(base + mt * 128) * DM);
  const char* B1g = (const char*)(w1T + ((size_t)e * DF + n0) * DM);
  const char* B2g = (const char*)(w2T + ((size_t)e * DF + n0) * DM);

  f32x4 acc1[4][2] = {};
  f32x4 acc2[4][2] = {};

  auto STAGE = [&](int buf, int k0) {
    const int kb = k0 * 2;
    char* s = sm[buf];
    gload16(Ag  + (size_t)srow * 2048 + kb + scolb,        s + w * 1024);
    gload16(Ag  + (size_t)(srow + 64) * 2048 + kb + scolb, s + 4096 + w * 1024);
    gload16(B1g + (size_t)srow * 2048 + kb + scolb,        s + 8192 + w * 1024);
    gload16(B2g + (size_t)srow * 2048 + kb + scolb,        s + 12288 + w * 1024);
  };

  STAGE(0, 0);
  asm volatile("s_waitcnt vmcnt(0)" ::: "memory");
  __syncthreads();

  int cur = 0;
  for (int k0 = 0; k0 < DM; k0 += 32) {
    if (k0 + 32 < DM) STAGE(cur ^ 1, k0 + 32);   // prefetch next tile; lands during MFMA
    const char* s = sm[cur];
    bf16x8 a[4], b1[2], b2[2];
#pragma unroll
    for (int m = 0; m < 4; ++m)
      a[m] = ldfrag(s + (wr * 64 + m * 16 + lrow) * 64 + lk * 16);
#pragma unroll
    for (int n = 0; n < 2; ++n) {
      b1[n] = ldfrag(s + 8192  + (wc * 32 + n * 16 + lrow) * 64 + lk * 16);
      b2[n] = ldfrag(s + 12288 + (wc * 32 + n * 16 + lrow) * 64 + lk * 16);
    }
#pragma unroll
    for (int m = 0; m < 4; ++m)
#pragma unroll
      for (int n = 0; n < 2; ++n) {
        acc1[m][n] = __builtin_amdgcn_mfma_f32_16x16x32_bf16(a[m], b1[n], acc1[m][n], 0, 0, 0);
        acc2[m][n] = __builtin_amdgcn_mfma_f32_16x16x32_bf16(a[m], b2[n], acc2[m][n], 0, 0, 0);
      }
    asm volatile("s_waitcnt vmcnt(0)" ::: "memory");
    __syncthreads();
    cur ^= 1;
  }

  u16* Hrow = H + (size_t)(base + mt * 128) * DF + n0;
#pragma unroll
  for (int m = 0; m < 4; ++m)
#pragma unroll
    for (int r = 0; r < 4; ++r) {
      const int rl = wr * 64 + m * 16 + lk * 4 + r;
      u16* hp = Hrow + (size_t)rl * DF + wc * 32 + lrow;
#pragma unroll
      for (int n = 0; n < 2; ++n) {
        const float h1 = acc1[m][n][r], h2 = acc2[m][n][r];
        const float sv = h1 / (1.f + __expf(-h1)) * h2;   // silu(h1)*h2
        hp[n * 16] = f2bf(sv);
      }
    }
}

// GEMM2: O_slot[slot] = wgt * (H @ w3^T')   -- plain stores, no atomics
// tile 128x128, 4 waves (2x2), per-wave 64x64 (m97 shape), BK=32, 2-phase prefetch
__global__ __launch_bounds__(256, 2)
void k_gemm2(const u16* __restrict__ H, const u16* __restrict__ w3T, const int* __restrict__ meta,
             const float* __restrict__ slot_weight, u16* __restrict__ O) {
  const int ti = blockIdx.y;
  if (ti >= meta[25]) return;
  const int ent = meta[32 + ti];
  const int e = ent & 255, mt = ent >> 8;
  const int base = meta[16 + e];
  const int n0 = blockIdx.x * 128;

  // per buffer: A[128][32] @0 (8KB) | B[128][32] @8192 (8KB)
  __shared__ __align__(16) char sm[2][16384];

  const int tid = threadIdx.x;
  const int lane = tid & 63;
  const int w = tid >> 6;
  const int wr = w >> 1, wc = w & 1;
  const int lrow = lane & 15, lk = lane >> 4;
  const int srow = tid >> 2;
  const int scolb = (tid & 3) * 16;

  const char* Ag = (const char*)(H + (size_t)(base + mt * 128) * DF);
  const char* Bg = (const char*)(w3T + ((size_t)e * DM + n0) * DF);

  f32x4 acc[4][4] = {};

  auto STAGE = [&](int buf, int k0) {
    const int kb = k0 * 2;
    char* s = sm[buf];
    gload16(Ag + (size_t)srow * 4096 + kb + scolb,        s + w * 1024);
    gload16(Ag + (size_t)(srow + 64) * 4096 + kb + scolb, s + 4096 + w * 1024);
    gload16(Bg + (size_t)srow * 4096 + kb + scolb,        s + 8192 + w * 1024);
    gload16(Bg + (size_t)(srow + 64) * 4096 + kb + scolb, s + 12288 + w * 1024);
  };

  STAGE(0, 0);
  asm volatile("s_waitcnt vmcnt(0)" ::: "memory");
  __syncthreads();

  int cur = 0;
  for (int k0 = 0; k0 < DF; k0 += 32) {
    if (k0 + 32 < DF) STAGE(cur ^ 1, k0 + 32);
    const char* s = sm[cur];
    bf16x8 a[4], b[4];
#pragma unroll
    for (int m = 0; m < 4; ++m)
      a[m] = ldfrag(s + (wr * 64 + m * 16 + lrow) * 64 + lk * 16);
#pragma unroll
    for (int n = 0; n < 4; ++n)
      b[n] = ldfrag(s + 8192 + (wc * 64 + n * 16 + lrow) * 64 + lk * 16);
#pragma unroll
    for (int m = 0; m < 4; ++m)
#pragma unroll
      for (int n = 0; n < 4; ++n)
        acc[m][n] = __builtin_amdgcn_mfma_f32_16x16x32_bf16(a[m], b[n], acc[m][n], 0, 0, 0);
    asm volatile("s_waitcnt vmcnt(0)" ::: "memory");
    __syncthreads();
    cur ^= 1;
  }

  const int sb = base + mt * 128;
#pragma unroll
  for (int m = 0; m < 4; ++m)
#pragma unroll
    for (int r = 0; r < 4; ++r) {
      const int rl = wr * 64 + m * 16 + lk * 4 + r;
      const float wgt = slot_weight[sb + rl];
      u16* op = O + (size_t)(sb + rl) * DM + n0 + wc * 64 + lrow;
#pragma unroll
      for (int n = 0; n < 4; ++n)
        op[n * 16] = f2bf(wgt * acc[m][n][r]);
    }
}

// out[t] = O[slot(2t)] + O[slot(2t+1)]
__global__ void k_combine(const u16* __restrict__ O, const int* __restrict__ pair_slot,
                          float* __restrict__ out) {
  const int t = blockIdx.x;
  const int c = threadIdx.x * 4;
  const int sa = pair_slot[2 * t], sb = pair_slot[2 * t + 1];
  const uint2 va = *reinterpret_cast<const uint2*>(O + (size_t)sa * DM + c);
  const uint2 vb = *reinterpret_cast<const uint2*>(O + (size_t)sb * DM + c);
  float4 r;
  r.x = __builtin_bit_cast(float, va.x << 16)          + __builtin_bit_cast(float, vb.x << 16);
  r.y = __builtin_bit_cast(float, va.x & 0xffff0000u)  + __builtin_bit_cast(float, vb.x & 0xffff0000u);
  r.z = __builtin_bit_cast(float, va.y << 16)          + __builtin_bit_cast(float, vb.y << 16);
  r.w = __builtin_bit_cast(float, va.y & 0xffff0000u)  + __builtin_bit_cast(float, vb.y & 0xffff0000u);
  *reinterpret_cast<float4*>(out + (size_t)t * DM + c) = r;
}

extern "C" void kernel_launch(void* const* d_in, const int* in_sizes, int n_in,
                              void* d_out, int out_size, void* d_ws, size_t ws_size,
                              hipStream_t stream) {
  const float* x  = (const float*)d_in[0];
  const int* eidx = (const int*)d_in[1];
  const float* ew = (const float*)d_in[2];
  const float* w1 = (const float*)d_in[3];
  const float* w2 = (const float*)d_in[4];
  const float* w3 = (const float*)d_in[5];
  float* out = (float*)d_out;
  char* ws = (char*)d_ws;

  int* meta          = (int*)ws;                           // 1 KB
  int* pair_slot     = (int*)(ws + 1024);                  // NP*4 = 64 KB
  int* slot_token    = (int*)(ws + 1024 + 65536);
  float* slot_weight = (float*)(ws + 1024 + 65536 + (size_t)MAXS * 4);
  size_t off = 1024 + 65536 + (size_t)MAXS * 8;
  u16* Xg  = (u16*)(ws + off); off += (size_t)MAXS * DM * 2;   // also reused as O_slot
  u16* w1T = (u16*)(ws + off); off += (size_t)NE * DM * DF * 2;
  u16* w2T = (u16*)(ws + off); off += (size_t)NE * DM * DF * 2;
  u16* w3T = (u16*)(ws + off); off += (size_t)NE * DM * DF * 2;
  u16* H   = (u16*)(ws + off);  // MAXS * DF * 2 bytes
  u16* O   = Xg;                // Xg is dead after k_gemm1

  k_init<<<(MAXS + 255) / 256, 256, 0, stream>>>(meta, slot_token);
  k_count<<<NP / 256, 256, 0, stream>>>(eidx, meta);
  k_scan<<<1, 64, 0, stream>>>(meta);
  k_fill<<<NP / 256, 256, 0, stream>>>(eidx, ew, meta, slot_token, slot_weight, pair_slot);
  k_gather<<<MAXS, 256, 0, stream>>>(x, slot_token, Xg);
  k_transpose<<<dim3(DF / 64, DM / 64, NE), 256, 0, stream>>>(w1, w1T, DM, DF);
  k_transpose<<<dim3(DF / 64, DM / 64, NE), 256, 0, stream>>>(w2, w2T, DM, DF);
  k_transpose<<<dim3(DM / 64, DF / 64, NE), 256, 0, stream>>>(w3, w3T, DF, DM);
  k_gemm1<<<dim3(DF / 64, MAXTILES, 1), 256, 0, stream>>>(Xg, w1T, w2T, H, meta);
  k_gemm2<<<dim3(DM / 128, MAXTILES, 1), 256, 0, stream>>>(H, w3T, meta, slot_weight, O);
  k_combine<<<NT, 256, 0, stream>>>(O, pair_slot, out);
}